// Round 4
// baseline (149.667 us; speedup 1.0000x reference)
//
#include <hip/hip_runtime.h>
#include <math.h>
#include <stdint.h>

// NetVLAD: N=32, C=512, P=1024, K=64, ALPHA=100. Split-bf16 MFMA.
// R11 = R10 with do{}while(0) statement-macros (R10 failed to compile:
// braced macro + if/else). Theory unchanged: latency-bound per R9 PMC
// (all pipes <20%, occupancy 15% = 8 waves/CU) -> 2x wave parallelism,
// halved per-wave chains.
//  - assign: grid 1024 = (n, 32p), 4 waves = (kh, C-half). kh-twins share a
//    cooperatively-staged x slice; C-partials combined in LDS; 16 waves/CU.
//  - vlad: 512-thread blocks, 8 waves = (kh, 4-way p-split); 16 waves/CU.
//  - both: accumulator split into 2 independent MFMA chains (s-parity);
//    one lgkmcnt-only barrier per chunk; 2-deep register prefetch.
#define ALPHA 100.0f
#define EPSN 1e-12f

typedef __attribute__((ext_vector_type(8))) short bf16x8;
typedef __attribute__((ext_vector_type(16))) float f32x16;
typedef __attribute__((ext_vector_type(4))) float f32x4;
typedef __attribute__((ext_vector_type(4))) unsigned int u32x4;

static __device__ __forceinline__ uint32_t f2bf(float f) {
    uint32_t u = __builtin_bit_cast(uint32_t, f);
    return (u + 0x7FFFu + ((u >> 16) & 1u)) >> 16;  // RNE
}
static __device__ __forceinline__ float bfhi(uint32_t u) {
    return __builtin_bit_cast(float, u & 0xFFFF0000u);
}
static __device__ __forceinline__ uint32_t packbf(float a, float b) {
    return f2bf(a) | (f2bf(b) << 16);
}
// CK block_sync_lds(): barrier that waits LDS ops only; global loads
// stay in flight across it (no vmcnt drain).
static __device__ __forceinline__ void lds_barrier() {
    asm volatile("s_waitcnt lgkmcnt(0)\n\ts_barrier" ::: "memory");
}

// ------- prep: v -> (vh, vl) bf16 split [k][c]; bias[k]; zero asum+knorm ----
__global__ __launch_bounds__(64) void prep_kernel(const float* __restrict__ v,
                                                  unsigned short* __restrict__ vh,
                                                  unsigned short* __restrict__ vl,
                                                  float* __restrict__ bias,
                                                  float* __restrict__ az) {
    int k = blockIdx.x, lane = threadIdx.x;
    az[k * 64 + lane] = 0.f;  // 4096 floats = asum(2048) + knorm(2048)
    const float* row = v + k * 512;
    float ssq = 0.f;
#pragma unroll
    for (int i = 0; i < 8; ++i) {
        int c = lane + 64 * i;
        float f = row[c];
        ssq = fmaf(f, f, ssq);
        uint32_t hi = f2bf(f);
        uint32_t lo = f2bf(f - __builtin_bit_cast(float, hi << 16));
        vh[k * 512 + c] = (unsigned short)hi;
        vl[k * 512 + c] = (unsigned short)lo;
    }
#pragma unroll
    for (int off = 32; off > 0; off >>= 1) ssq += __shfl_xor(ssq, off, 64);
    if (lane == 0) bias[k] = -ALPHA * sqrtf(ssq);
}

// ================= P1 assign: D[k][p] = sum_c v[k][c]*x[c][p] ===============
// grid 1024 = (n, 32-p block); block 256 = 4 waves: kh = k-half, ch = C-half.
// Each wave: 8 chunks of 32c x 32p. kh-twins co-stage one x slice per ch.
__global__ __launch_bounds__(256) void assign_kernel(
    const float* __restrict__ x, const unsigned short* __restrict__ vh,
    const unsigned short* __restrict__ vl, const float* __restrict__ bias,
    unsigned short* __restrict__ aT, float* __restrict__ asum) {
    __shared__ uint32_t xsh[2][2][16 * 36];  // [ch][dbuf] hi plane
    __shared__ uint32_t xsl[2][2][16 * 36];  // [ch][dbuf] lo plane
    __shared__ float cmb[2][64][17];         // ch=1 partial acc
    __shared__ float __attribute__((aligned(16))) ssq_w[4][32];
    __shared__ float bias_l[64];
    __shared__ float xchm[2][32];
    __shared__ float xchs[2][32];

    int tid = threadIdx.x, bx = blockIdx.x;
    int n = bx >> 5, pblk = (bx & 31) << 5;
    int l = tid & 63, w = tid >> 6;
    int kh = w & 1, ch = w >> 1;
    int h = l >> 5, cl = l & 31;
    // staging mapping within the ch-pair (128 threads): row-pair j, p-quad q
    int sid = kh * 64 + l;
    int j = sid >> 3, q = sid & 7;

    if (tid < 64) bias_l[tid] = bias[tid];

    const float* xg = x + (size_t)n * 524288 + (size_t)(ch * 256 + 2 * j) * 1024 +
                      pblk + 4 * q;
    const unsigned short* vhg = vh + (size_t)(32 * kh + cl) * 512 + ch * 256 + 8 * h;
    const unsigned short* vlg = vl + (size_t)(32 * kh + cl) * 512 + ch * 256 + 8 * h;

    f32x16 accA, accB;
#pragma unroll
    for (int r = 0; r < 16; ++r) { accA[r] = 0.f; accB[r] = 0.f; }
    f32x4 ssqv;
#pragma unroll
    for (int i = 0; i < 4; ++i) ssqv[i] = 0.f;

    float4 xv[2][2];             // [slot][row a/b]
    u32x4 vfh[2][2], vfl[2][2];  // [slot][s]

#define A_LOADX(slot, cc)                                                      \
    do {                                                                       \
        const float* p_ = xg + (size_t)(cc)*32768;                             \
        xv[slot][0] = *(const float4*)p_;                                      \
        xv[slot][1] = *(const float4*)(p_ + 1024);                             \
    } while (0)
#define A_LOADV(slot, cc)                                                      \
    do {                                                                       \
        vfh[slot][0] = *(const u32x4*)(vhg + (cc)*32);                         \
        vfh[slot][1] = *(const u32x4*)(vhg + (cc)*32 + 16);                    \
        vfl[slot][0] = *(const u32x4*)(vlg + (cc)*32);                         \
        vfl[slot][1] = *(const u32x4*)(vlg + (cc)*32 + 16);                    \
    } while (0)
#define A_STAGE(buf, slot)                                                     \
    do {                                                                       \
        float fa[4] = {xv[slot][0].x, xv[slot][0].y, xv[slot][0].z,            \
                       xv[slot][0].w};                                         \
        float fb[4] = {xv[slot][1].x, xv[slot][1].y, xv[slot][1].z,            \
                       xv[slot][1].w};                                         \
        u32x4 hp, lp;                                                          \
        _Pragma("unroll") for (int i = 0; i < 4; ++i) {                        \
            uint32_t h0 = f2bf(fa[i]);                                         \
            uint32_t l0 = f2bf(fa[i] - bfhi(h0 << 16));                        \
            uint32_t h1 = f2bf(fb[i]);                                         \
            uint32_t l1 = f2bf(fb[i] - bfhi(h1 << 16));                        \
            hp[i] = h0 | (h1 << 16);                                           \
            lp[i] = l0 | (l1 << 16);                                           \
            ssqv[i] = fmaf(fa[i], fa[i], fmaf(fb[i], fb[i], ssqv[i]));         \
        }                                                                      \
        *(u32x4*)&xsh[ch][buf][j * 36 + 4 * q] = hp;                           \
        *(u32x4*)&xsl[ch][buf][j * 36 + 4 * q] = lp;                           \
    } while (0)
#define A_COMPUTE(buf, slot)                                                   \
    do {                                                                       \
        { /* s = 0 -> accA */                                                  \
            int xb = (4 * h) * 36 + cl;                                        \
            u32x4 bhp, blp;                                                    \
            _Pragma("unroll") for (int q2 = 0; q2 < 4; ++q2) {                 \
                bhp[q2] = xsh[ch][buf][xb + q2 * 36];                          \
                blp[q2] = xsl[ch][buf][xb + q2 * 36];                          \
            }                                                                  \
            bf16x8 ah = __builtin_bit_cast(bf16x8, vfh[slot][0]);              \
            bf16x8 al = __builtin_bit_cast(bf16x8, vfl[slot][0]);              \
            bf16x8 xh = __builtin_bit_cast(bf16x8, bhp);                       \
            bf16x8 xl = __builtin_bit_cast(bf16x8, blp);                       \
            accA = __builtin_amdgcn_mfma_f32_32x32x16_bf16(ah, xh, accA, 0, 0, 0);\
            accA = __builtin_amdgcn_mfma_f32_32x32x16_bf16(ah, xl, accA, 0, 0, 0);\
            accA = __builtin_amdgcn_mfma_f32_32x32x16_bf16(al, xh, accA, 0, 0, 0);\
        }                                                                      \
        { /* s = 1 -> accB */                                                  \
            int xb = (8 + 4 * h) * 36 + cl;                                    \
            u32x4 bhp, blp;                                                    \
            _Pragma("unroll") for (int q2 = 0; q2 < 4; ++q2) {                 \
                bhp[q2] = xsh[ch][buf][xb + q2 * 36];                          \
                blp[q2] = xsl[ch][buf][xb + q2 * 36];                          \
            }                                                                  \
            bf16x8 ah = __builtin_bit_cast(bf16x8, vfh[slot][1]);              \
            bf16x8 al = __builtin_bit_cast(bf16x8, vfl[slot][1]);              \
            bf16x8 xh = __builtin_bit_cast(bf16x8, bhp);                       \
            bf16x8 xl = __builtin_bit_cast(bf16x8, blp);                       \
            accB = __builtin_amdgcn_mfma_f32_32x32x16_bf16(ah, xh, accB, 0, 0, 0);\
            accB = __builtin_amdgcn_mfma_f32_32x32x16_bf16(ah, xl, accB, 0, 0, 0);\
            accB = __builtin_amdgcn_mfma_f32_32x32x16_bf16(al, xh, accB, 0, 0, 0);\
        }                                                                      \
    } while (0)

    A_LOADX(0, 0);
    A_LOADV(0, 0);
    A_LOADX(1, 1);
    A_LOADV(1, 1);
    A_STAGE(0, 0);
    lds_barrier();
#pragma unroll
    for (int cc = 0; cc < 8; ++cc) {
        int cur = cc & 1;
        if (cc < 7) {
            if (cur == 0) A_STAGE(1, 1);
            else A_STAGE(0, 0);
        }
        if (cur == 0) A_COMPUTE(0, 0);
        else A_COMPUTE(1, 1);
        if (cc < 6) {
            if (cur == 0) { A_LOADX(0, cc + 2); A_LOADV(0, cc + 2); }
            else          { A_LOADX(1, cc + 2); A_LOADV(1, cc + 2); }
        }
        lds_barrier();
    }
#undef A_LOADX
#undef A_LOADV
#undef A_STAGE
#undef A_COMPUTE

    // ---- epilogue: ssq wave-reduce, ch-combine, softmax over 64 k ----
#pragma unroll
    for (int i = 0; i < 4; ++i) {
        float v = ssqv[i];
        v += __shfl_xor(v, 8, 64);
        v += __shfl_xor(v, 16, 64);
        v += __shfl_xor(v, 32, 64);
        ssqv[i] = v;
    }
    if (l < 8) *(f32x4*)&ssq_w[w][4 * l] = ssqv;
    if (ch == 1) {
#pragma unroll
        for (int r = 0; r < 16; ++r) cmb[kh][l][r] = accA[r] + accB[r];
    }
    __syncthreads();

    float m = -INFINITY, ssum = 0.f, sinv = 0.f, e[16];
    if (ch == 0) {
        float ssq = ssq_w[0][cl] + ssq_w[1][cl] + ssq_w[2][cl] + ssq_w[3][cl];
        sinv = 1.0f / fmaxf(sqrtf(ssq), EPSN);
        float twoAs = 2.0f * ALPHA * sinv;
#pragma unroll
        for (int r = 0; r < 16; ++r) {
            int k = (r & 3) + 8 * (r >> 2) + 4 * h + 32 * kh;
            float dv = accA[r] + accB[r] + cmb[kh][l][r];
            float lv = fmaf(twoAs, dv, bias_l[k]);
            e[r] = lv;
            m = fmaxf(m, lv);
        }
        m = fmaxf(m, __shfl_xor(m, 32, 64));
    }
    if (ch == 0 && l < 32) xchm[kh][l] = m;
    __syncthreads();
    if (ch == 0) {
        m = fmaxf(m, xchm[1 - kh][cl]);
#pragma unroll
        for (int r = 0; r < 16; ++r) {
            e[r] = expf(e[r] - m);
            ssum += e[r];
        }
        ssum += __shfl_xor(ssum, 32, 64);
    }
    if (ch == 0 && l < 32) xchs[kh][l] = ssum;
    __syncthreads();
    if (ch == 0) {
        ssum += xchs[1 - kh][cl];
        float rs = 1.0f / ssum;
        float a2s = rs * sinv;  // a2 = a*sinv (scale folded into a-side)
        unsigned short* aTn = aT + (size_t)n * 65536 + pblk + cl;
#pragma unroll
        for (int r = 0; r < 16; ++r) {
            int k = (r & 3) + 8 * (r >> 2) + 4 * h + 32 * kh;
            aTn[(size_t)k * 1024] = (unsigned short)f2bf(e[r] * a2s);
            float red = e[r] * rs;
#pragma unroll
            for (int off = 1; off <= 16; off <<= 1) red += __shfl_xor(red, off, 64);
            if (cl == 0) atomicAdd(&asum[n * 64 + k], red);
        }
    }
}

// ================= P2 vlad: D[k][c] = sum_p a2[k][p]*bf16(x)[c][p] ==========
// grid 512 = (n, 32-c block); block 512 = 8 waves (kh, 4-way p-split).
__global__ __launch_bounds__(512) void vlad_kernel(
    const float* __restrict__ x, const unsigned short* __restrict__ aT,
    const float* __restrict__ asum, const float* __restrict__ vocabs,
    float* __restrict__ out, float* __restrict__ knorm) {
    __shared__ uint32_t xt[2][32 * 34];
    __shared__ uint32_t at[2][64 * 34];
    __shared__ float cmb[3][2][64][17];
    __shared__ float asum_l[64];

    int tid = threadIdx.x, bx = blockIdx.x;
    int n = bx >> 4, cb = (bx & 15) << 5;
    int l = tid & 63, w = tid >> 6;
    int kh = w & 1, ps = w >> 1;
    int h = l >> 5, cl = l & 31;

    if (tid < 64) asum_l[tid] = asum[n * 64 + tid];

    int xr = tid >> 4, xq = tid & 15;  // x: row cb+xr, p-quad xq
    int ak = tid >> 3, aq = tid & 7;   // a: k-row ak, p-oct aq

    const float* xg = x + (size_t)n * 524288 + (size_t)(cb + xr) * 1024 + 4 * xq;
    const unsigned short* ag = aT + (size_t)n * 65536 + (size_t)ak * 1024 + 8 * aq;

    f32x16 accA, accB;
#pragma unroll
    for (int r = 0; r < 16; ++r) { accA[r] = 0.f; accB[r] = 0.f; }

    float4 qx[2];
    u32x4 qa[2];

#define V_LOAD(slot, chk)                                                      \
    do {                                                                       \
        qx[slot] = *(const float4*)(xg + (chk)*64);                            \
        qa[slot] = *(const u32x4*)(ag + (chk)*64);                             \
    } while (0)
#define V_STAGE(buf, slot)                                                     \
    do {                                                                       \
        *(uint2*)&xt[buf][xr * 34 + 2 * xq] =                                  \
            make_uint2(packbf(qx[slot].x, qx[slot].y),                         \
                       packbf(qx[slot].z, qx[slot].w));                        \
        *(uint2*)&at[buf][ak * 34 + 4 * aq] =                                  \
            make_uint2(qa[slot][0], qa[slot][1]);                              \
        *(uint2*)&at[buf][ak * 34 + 4 * aq + 2] =                              \
            make_uint2(qa[slot][2], qa[slot][3]);                              \
    } while (0)
#define V_COMP(buf)                                                            \
    do {                                                                       \
        _Pragma("unroll") for (int s = 0; s < 4; ++s) {                        \
            int va = (32 * kh + cl) * 34 + 8 * s + 4 * h;                      \
            uint2 f0 = *(const uint2*)&at[buf][va];                            \
            uint2 f1 = *(const uint2*)&at[buf][va + 2];                        \
            int vb = cl * 34 + 8 * s + 4 * h;                                  \
            uint2 g0 = *(const uint2*)&xt[buf][vb];                            \
            uint2 g1 = *(const uint2*)&xt[buf][vb + 2];                        \
            u32x4 afp, bfp;                                                    \
            afp[0] = f0.x; afp[1] = f0.y; afp[2] = f1.x; afp[3] = f1.y;        \
            bfp[0] = g0.x; bfp[1] = g0.y; bfp[2] = g1.x; bfp[3] = g1.y;        \
            f32x16& accr = (s & 1) ? accB : accA;                              \
            accr = __builtin_amdgcn_mfma_f32_32x32x16_bf16(                    \
                __builtin_bit_cast(bf16x8, afp), __builtin_bit_cast(bf16x8, bfp),\
                accr, 0, 0, 0);                                                \
        }                                                                      \
    } while (0)

    V_LOAD(0, 0);
    V_LOAD(1, 1);
    V_STAGE(0, 0);
    lds_barrier();
#pragma unroll
    for (int chk = 0; chk < 16; ++chk) {
        int cur = chk & 1;
        if (chk < 15) {
            if (cur == 0) V_STAGE(1, 1);
            else V_STAGE(0, 0);
        }
        if (ps == (chk & 3)) {
            if (cur == 0) V_COMP(0);
            else V_COMP(1);
        }
        if (chk < 14) {
            if (cur == 0) V_LOAD(0, chk + 2);
            else V_LOAD(1, chk + 2);
        }
        lds_barrier();
    }
#undef V_LOAD
#undef V_STAGE
#undef V_COMP

    // ---- epilogue: 4-way p combine, -asum*v, store, knorm ----
    if (ps != 0) {
#pragma unroll
        for (int r = 0; r < 16; ++r) cmb[ps - 1][kh][l][r] = accA[r] + accB[r];
    }
    __syncthreads();
    if (ps == 0) {
#pragma unroll
        for (int r = 0; r < 16; ++r) {
            int k = (r & 3) + 8 * (r >> 2) + 4 * h + 32 * kh;
            int c = cb + cl;
            float val = accA[r] + accB[r] + cmb[0][kh][l][r] + cmb[1][kh][l][r] +
                        cmb[2][kh][l][r];
            val = fmaf(-asum_l[k], vocabs[k * 512 + c], val);
            out[(size_t)n * 32768 + (size_t)k * 512 + c] = val;
            float t2 = val * val;
#pragma unroll
            for (int off = 1; off <= 16; off <<= 1) t2 += __shfl_xor(t2, off, 64);
            if (cl == 0) atomicAdd(&knorm[n * 64 + k], t2);
        }
    }
}

// ---------------- scale: intra-norm (per k) * global norm (per n), in place -
__global__ __launch_bounds__(256) void scale_kernel(float* __restrict__ out,
                                                    const float* __restrict__ knorm) {
    int n = blockIdx.y;
    int sb = blockIdx.x;
    int tid = threadIdx.x;
    __shared__ float sc[64];
    __shared__ float tots;
    if (tid < 64) {
        float kn = knorm[n * 64 + tid];
        float nk = sqrtf(kn);
        float inv = 1.0f / fmaxf(nk, EPSN);
        sc[tid] = inv;
        float t = nk * inv;
        float t2 = t * t;
#pragma unroll
        for (int off = 32; off > 0; off >>= 1) t2 += __shfl_xor(t2, off, 64);
        if (tid == 0) tots = t2;
    }
    __syncthreads();
    float invt = 1.0f / fmaxf(sqrtf(tots), EPSN);
    float* base = out + (size_t)n * 32768 + sb * 4096;
#pragma unroll
    for (int i = 0; i < 16; ++i) {
        int idx = tid + 256 * i;
        int k = (sb * 4096 + idx) >> 9;
        base[idx] *= sc[k] * invt;
    }
}

extern "C" void kernel_launch(void* const* d_in, const int* in_sizes, int n_in,
                              void* d_out, int out_size, void* d_ws, size_t ws_size,
                              hipStream_t stream) {
    const float* x = (const float*)d_in[0];       // [32,512,32,32]
    const float* vocabs = (const float*)d_in[1];  // [64,512]
    float* out = (float*)d_out;                   // [32, 32768]
    char* ws = (char*)d_ws;
    unsigned short* vh = (unsigned short*)(ws);            // 65536 B
    unsigned short* vl = (unsigned short*)(ws + 65536);    // 65536 B
    float* bias  = (float*)(ws + 131072);                  //   256 B
    float* asum  = (float*)(ws + 131328);                  //  8192 B
    float* knorm = (float*)(ws + 139520);                  //  8192 B
    unsigned short* aT = (unsigned short*)(ws + 147712);   // 4 MB : a2 [n][k][p]

    prep_kernel<<<64, 64, 0, stream>>>(vocabs, vh, vl, bias, asum);  // zeroes asum+knorm
    assign_kernel<<<1024, 256, 0, stream>>>(x, vh, vl, bias, aT, asum);
    vlad_kernel<<<512, 512, 0, stream>>>(x, aT, asum, vocabs, out, knorm);
    scale_kernel<<<dim3(8, 32), 256, 0, stream>>>(out, knorm);
}

// Round 6
// 144.172 us; speedup vs baseline: 1.0381x; 1.0381x over previous
//
#include <hip/hip_runtime.h>
#include <math.h>
#include <stdint.h>

// NetVLAD: N=32, C=512, P=1024, K=64, ALPHA=100. Split-bf16 MFMA.
// R13 = R12 resubmitted (R12 bench was an infra failure: container died,
// kernel never ran). Theory unchanged:
// assign rebuilt for DRAM burst efficiency (R2..R11 PMC: clock OK,
// pipes idle, latency/burst-bound; perf correlates with contiguous run
// length per x-row visit: 256B->40us, 128B->44-50us at ~700GB/s).
//  - assign: grid 256 = (n, 128-p tile); 512 thr = 8 waves (kh, p-quarter).
//    Load phases read 512B contiguous per x row (32 lanes x 16B).
//    16 c-chunks; 3-slot register prefetch (~2 phases of latency cover);
//    lockstep lgkmcnt-only barrier (proven fastest); split accumulators.
//  - vlad/prep/scale: proven R8 versions verbatim (isolate the experiment).
#define ALPHA 100.0f
#define EPSN 1e-12f

typedef __attribute__((ext_vector_type(8))) short bf16x8;
typedef __attribute__((ext_vector_type(16))) float f32x16;
typedef __attribute__((ext_vector_type(4))) float f32x4;
typedef __attribute__((ext_vector_type(4))) unsigned int u32x4;

static __device__ __forceinline__ uint32_t f2bf(float f) {
    uint32_t u = __builtin_bit_cast(uint32_t, f);
    return (u + 0x7FFFu + ((u >> 16) & 1u)) >> 16;  // RNE
}
static __device__ __forceinline__ float bfhi(uint32_t u) {
    return __builtin_bit_cast(float, u & 0xFFFF0000u);
}
static __device__ __forceinline__ uint32_t packbf(float a, float b) {
    return f2bf(a) | (f2bf(b) << 16);
}
// CK block_sync_lds(): barrier that waits LDS ops only; global loads
// stay in flight across it (no vmcnt drain).
static __device__ __forceinline__ void lds_barrier() {
    asm volatile("s_waitcnt lgkmcnt(0)\n\ts_barrier" ::: "memory");
}

// ------- prep: v -> (vh, vl) bf16 split [k][c]; bias[k]; zero asum+knorm ----
__global__ __launch_bounds__(64) void prep_kernel(const float* __restrict__ v,
                                                  unsigned short* __restrict__ vh,
                                                  unsigned short* __restrict__ vl,
                                                  float* __restrict__ bias,
                                                  float* __restrict__ az) {
    int k = blockIdx.x, lane = threadIdx.x;
    az[k * 64 + lane] = 0.f;  // 4096 floats = asum(2048) + knorm(2048)
    const float* row = v + k * 512;
    float ssq = 0.f;
#pragma unroll
    for (int i = 0; i < 8; ++i) {
        int c = lane + 64 * i;
        float f = row[c];
        ssq = fmaf(f, f, ssq);
        uint32_t hi = f2bf(f);
        uint32_t lo = f2bf(f - __builtin_bit_cast(float, hi << 16));
        vh[k * 512 + c] = (unsigned short)hi;
        vl[k * 512 + c] = (unsigned short)lo;
    }
#pragma unroll
    for (int off = 32; off > 0; off >>= 1) ssq += __shfl_xor(ssq, off, 64);
    if (lane == 0) bias[k] = -ALPHA * sqrtf(ssq);
}

// ================= P1 assign: D[k][p] = sum_c v[k][c]*x[c][p] ===============
// grid 256 = (n, 128-p tile); block 512 = 8 waves: (kh, ps = p-quarter).
// 16 chunks of 32 c. Staging: thread (r=tid>>5, q=tid&31) loads x rows
// {2r,2r+1} at p = 4q (wave covers 512B contiguous per row).
__global__ __launch_bounds__(512) void assign_kernel(
    const float* __restrict__ x, const unsigned short* __restrict__ vh,
    const unsigned short* __restrict__ vl, const float* __restrict__ bias,
    unsigned short* __restrict__ aT, float* __restrict__ asum) {
    __shared__ uint32_t xsh[2][16 * 132];  // [dbuf][c-pair][128p +pad]
    __shared__ uint32_t xsl[2][16 * 132];
    __shared__ float ssq_s[16][132];
    __shared__ float ssq_l[128];
    __shared__ float bias_l[64];
    __shared__ float xchm[4][2][32];
    __shared__ float xchs[4][2][32];

    int tid = threadIdx.x, bx = blockIdx.x;
    int n = bx >> 3, pblk = (bx & 7) << 7;
    int l = tid & 63, w = tid >> 6;
    int kh = w & 1, ps = w >> 1;  // ps in 0..3
    int h = l >> 5, cl = l & 31;
    int r = tid >> 5, q = tid & 31;  // staging: c-pair r, p-quad q

    if (tid < 64) bias_l[tid] = bias[tid];

    const float* xg = x + (size_t)n * 524288 + (size_t)(2 * r) * 1024 + pblk + 4 * q;
    const unsigned short* vhg = vh + (size_t)(32 * kh + cl) * 512 + 8 * h;
    const unsigned short* vlg = vl + (size_t)(32 * kh + cl) * 512 + 8 * h;

    f32x16 accA, accB;
#pragma unroll
    for (int i = 0; i < 16; ++i) { accA[i] = 0.f; accB[i] = 0.f; }
    f32x4 ssqv;
#pragma unroll
    for (int i = 0; i < 4; ++i) ssqv[i] = 0.f;

    float4 xa[3], xb[3];
    u32x4 vfh[3][2], vfl[3][2];

#define A_LOAD(slot, cc)                                                       \
    do {                                                                       \
        xa[slot] = *(const float4*)(xg + (size_t)(cc)*32768);                  \
        xb[slot] = *(const float4*)(xg + (size_t)(cc)*32768 + 1024);           \
        vfh[slot][0] = *(const u32x4*)(vhg + (cc)*32);                         \
        vfh[slot][1] = *(const u32x4*)(vhg + (cc)*32 + 16);                    \
        vfl[slot][0] = *(const u32x4*)(vlg + (cc)*32);                         \
        vfl[slot][1] = *(const u32x4*)(vlg + (cc)*32 + 16);                    \
    } while (0)
#define A_STAGE(buf, slot)                                                     \
    do {                                                                       \
        float fa[4] = {xa[slot].x, xa[slot].y, xa[slot].z, xa[slot].w};        \
        float fb[4] = {xb[slot].x, xb[slot].y, xb[slot].z, xb[slot].w};        \
        u32x4 hp, lp;                                                          \
        _Pragma("unroll") for (int i = 0; i < 4; ++i) {                        \
            uint32_t h0 = f2bf(fa[i]);                                         \
            uint32_t l0 = f2bf(fa[i] - bfhi(h0 << 16));                        \
            uint32_t h1 = f2bf(fb[i]);                                         \
            uint32_t l1 = f2bf(fb[i] - bfhi(h1 << 16));                        \
            hp[i] = h0 | (h1 << 16);                                           \
            lp[i] = l0 | (l1 << 16);                                           \
            ssqv[i] = fmaf(fa[i], fa[i], fmaf(fb[i], fb[i], ssqv[i]));         \
        }                                                                      \
        *(u32x4*)&xsh[buf][r * 132 + 4 * q] = hp;                              \
        *(u32x4*)&xsl[buf][r * 132 + 4 * q] = lp;                              \
    } while (0)
#define A_COMPUTE(buf, slot)                                                   \
    do {                                                                       \
        _Pragma("unroll") for (int s = 0; s < 2; ++s) {                        \
            int xb_ = (8 * s + 4 * h) * 132 + 32 * ps + cl;                    \
            u32x4 bhp, blp;                                                    \
            _Pragma("unroll") for (int q2 = 0; q2 < 4; ++q2) {                 \
                bhp[q2] = xsh[buf][xb_ + q2 * 132];                            \
                blp[q2] = xsl[buf][xb_ + q2 * 132];                            \
            }                                                                  \
            bf16x8 ah = __builtin_bit_cast(bf16x8, vfh[slot][s]);              \
            bf16x8 al = __builtin_bit_cast(bf16x8, vfl[slot][s]);              \
            bf16x8 xh_ = __builtin_bit_cast(bf16x8, bhp);                      \
            bf16x8 xl_ = __builtin_bit_cast(bf16x8, blp);                      \
            f32x16& accr = s ? accB : accA;                                    \
            accr = __builtin_amdgcn_mfma_f32_32x32x16_bf16(ah, xh_, accr, 0, 0, 0);\
            accr = __builtin_amdgcn_mfma_f32_32x32x16_bf16(ah, xl_, accr, 0, 0, 0);\
            accr = __builtin_amdgcn_mfma_f32_32x32x16_bf16(al, xh_, accr, 0, 0, 0);\
        }                                                                      \
    } while (0)

    A_LOAD(0, 0);
    A_LOAD(1, 1);
    A_LOAD(2, 2);
    A_STAGE(0, 0);
    lds_barrier();
#pragma unroll
    for (int cc = 0; cc < 16; ++cc) {
        if (cc < 15) A_STAGE((cc + 1) & 1, (cc + 1) % 3);
        A_COMPUTE(cc & 1, cc % 3);
        if (cc < 13) A_LOAD(cc % 3, cc + 3);
        lds_barrier();
    }
#undef A_LOAD
#undef A_STAGE
#undef A_COMPUTE

    // ---- epilogue: ssq cross-thread reduce, softmax over 64 k per p ----
    *(f32x4*)&ssq_s[r][4 * q] = ssqv;
    __syncthreads();
    if (tid < 128) {
        float s = 0.f;
#pragma unroll
        for (int rr = 0; rr < 16; ++rr) s += ssq_s[rr][tid];
        ssq_l[tid] = s;
    }
    __syncthreads();
    float ssq = ssq_l[32 * ps + cl];
    float sinv = 1.0f / fmaxf(sqrtf(ssq), EPSN);
    float twoAs = 2.0f * ALPHA * sinv;
    float e[16];
    float m = -INFINITY;
#pragma unroll
    for (int rr = 0; rr < 16; ++rr) {
        int k = (rr & 3) + 8 * (rr >> 2) + 4 * h + 32 * kh;
        float lv = fmaf(twoAs, accA[rr] + accB[rr], bias_l[k]);
        e[rr] = lv;
        m = fmaxf(m, lv);
    }
    m = fmaxf(m, __shfl_xor(m, 32, 64));
    if (l < 32) xchm[ps][kh][l] = m;
    __syncthreads();
    m = fmaxf(m, xchm[ps][1 - kh][cl]);
    float ssum = 0.f;
#pragma unroll
    for (int rr = 0; rr < 16; ++rr) {
        e[rr] = expf(e[rr] - m);
        ssum += e[rr];
    }
    ssum += __shfl_xor(ssum, 32, 64);
    if (l < 32) xchs[ps][kh][l] = ssum;
    __syncthreads();
    ssum += xchs[ps][1 - kh][cl];
    float rs = 1.0f / ssum;
    float a2s = rs * sinv;  // a2 = a*sinv (scale folded into a-side)
    unsigned short* aTn = aT + (size_t)n * 65536 + pblk + 32 * ps + cl;
#pragma unroll
    for (int rr = 0; rr < 16; ++rr) {
        int k = (rr & 3) + 8 * (rr >> 2) + 4 * h + 32 * kh;
        aTn[(size_t)k * 1024] = (unsigned short)f2bf(e[rr] * a2s);
        float red = e[rr] * rs;
#pragma unroll
        for (int off = 1; off <= 16; off <<= 1) red += __shfl_xor(red, off, 64);
        if (cl == 0) atomicAdd(&asum[n * 64 + k], red);
    }
}

// ======================= P2 vlad helpers (R8 verbatim) ======================
static __device__ __forceinline__ void v_load(float4& qxa, float4& qxb,
                                              u32x4& qa0, u32x4& qa1,
                                              const float* xg,
                                              const unsigned short* ag, int p0) {
    qxa = *(const float4*)(xg + p0);
    qxb = *(const float4*)(xg + p0 + 32);
    qa0 = *(const u32x4*)(ag + p0);
    qa1 = *(const u32x4*)(ag + p0 + 8);
}
static __device__ __forceinline__ void v_stage(uint32_t* xtb, uint32_t* atb,
                                               const float4 qxa, const float4 qxb,
                                               const u32x4 qa0, const u32x4 qa1,
                                               int xr, int xq, int ak, int aj) {
    int xb = xr * 34 + (xq >> 1);
    *(uint2*)&xtb[xb] = make_uint2(packbf(qxa.x, qxa.y), packbf(qxa.z, qxa.w));
    *(uint2*)&xtb[xb + 16] = make_uint2(packbf(qxb.x, qxb.y), packbf(qxb.z, qxb.w));
    int ab = ak * 34 + (aj >> 1);
    *(uint2*)&atb[ab] = make_uint2(qa0[0], qa0[1]);
    *(uint2*)&atb[ab + 2] = make_uint2(qa0[2], qa0[3]);
    *(uint2*)&atb[ab + 4] = make_uint2(qa1[0], qa1[1]);
    *(uint2*)&atb[ab + 6] = make_uint2(qa1[2], qa1[3]);
}
static __device__ __forceinline__ void v_compute(const uint32_t* xtb,
                                                 const uint32_t* atb,
                                                 f32x16& acc, int kh, int h,
                                                 int cl) {
#pragma unroll
    for (int s = 0; s < 4; ++s) {
        int va = (32 * kh + cl) * 34 + 8 * s + 4 * h;
        uint2 f0 = *(const uint2*)&atb[va];
        uint2 f1 = *(const uint2*)&atb[va + 2];
        int vb = cl * 34 + 8 * s + 4 * h;
        uint2 g0 = *(const uint2*)&xtb[vb];
        uint2 g1 = *(const uint2*)&xtb[vb + 2];
        u32x4 afp, bfp;
        afp[0] = f0.x; afp[1] = f0.y; afp[2] = f1.x; afp[3] = f1.y;
        bfp[0] = g0.x; bfp[1] = g0.y; bfp[2] = g1.x; bfp[3] = g1.y;
        acc = __builtin_amdgcn_mfma_f32_32x32x16_bf16(
            __builtin_bit_cast(bf16x8, afp), __builtin_bit_cast(bf16x8, bfp),
            acc, 0, 0, 0);
    }
}

// ================= P2 vlad: D[k][c] = sum_p a2[k][p]*bf16(x)[c][p] ==========
// grid 512 = (n, 32-c block); block 256 = 4 waves (kh, p-parity).
__global__ __launch_bounds__(256) void vlad_kernel(
    const float* __restrict__ x, const unsigned short* __restrict__ aT,
    const float* __restrict__ asum, const float* __restrict__ vocabs,
    float* __restrict__ out, float* __restrict__ knorm) {
    __shared__ uint32_t xt[2][32 * 34];
    __shared__ uint32_t at[2][64 * 34];
    __shared__ float cmb[2][64][16];
    __shared__ float asum_l[64];

    int tid = threadIdx.x, bx = blockIdx.x;
    int n = bx >> 4, cb = (bx & 15) << 5;
    int l = tid & 63, w = tid >> 6;
    int kh = w & 1, ps = w >> 1;
    int h = l >> 5, cl = l & 31;

    if (tid < 64) asum_l[tid] = asum[n * 64 + tid];

    int xr = tid >> 3, xq = (tid & 7) << 2;
    int ak = tid >> 2, aj = (tid & 3) << 4;

    const float* xg = x + (size_t)n * 524288 + (size_t)(cb + xr) * 1024 + xq;
    const unsigned short* ag = aT + (size_t)n * 65536 + (size_t)ak * 1024 + aj;

    f32x16 acc;
#pragma unroll
    for (int i = 0; i < 16; ++i) acc[i] = 0.f;

    float4 qxa[2], qxb[2];
    u32x4 qa0[2], qa1[2];
    v_load(qxa[0], qxb[0], qa0[0], qa1[0], xg, ag, 0);
    v_load(qxa[1], qxb[1], qa0[1], qa1[1], xg, ag, 64);
    __syncthreads();  // asum_l visible
    v_stage(xt[0], at[0], qxa[0], qxb[0], qa0[0], qa1[0], xr, xq, ak, aj);
    lds_barrier();
#pragma unroll
    for (int cc = 0; cc < 8; ++cc) {
        // even ch = 2cc (computed by ps==0 waves)
        v_stage(xt[1], at[1], qxa[1], qxb[1], qa0[1], qa1[1], xr, xq, ak, aj);
        if (cc < 7)
            v_load(qxa[0], qxb[0], qa0[0], qa1[0], xg, ag, (2 * cc + 2) << 6);
        if (ps == 0) v_compute(xt[0], at[0], acc, kh, h, cl);
        lds_barrier();
        // odd ch = 2cc+1 (computed by ps==1 waves)
        if (cc < 7) {
            v_stage(xt[0], at[0], qxa[0], qxb[0], qa0[0], qa1[0], xr, xq, ak, aj);
            v_load(qxa[1], qxb[1], qa0[1], qa1[1], xg, ag, (2 * cc + 3) << 6);
        }
        if (ps == 1) v_compute(xt[1], at[1], acc, kh, h, cl);
        lds_barrier();
    }
    // ---- epilogue: parity combine, -asum*v, store, knorm ----
    __syncthreads();
    if (ps == 1) {
#pragma unroll
        for (int i = 0; i < 16; ++i) cmb[kh][l][i] = acc[i];
    }
    __syncthreads();
    if (ps == 0) {
#pragma unroll
        for (int i = 0; i < 16; ++i) {
            int k = (i & 3) + 8 * (i >> 2) + 4 * h + 32 * kh;
            int c = cb + cl;
            float val = acc[i] + cmb[kh][l][i];
            val = fmaf(-asum_l[k], vocabs[k * 512 + c], val);
            out[(size_t)n * 32768 + (size_t)k * 512 + c] = val;
            float t2 = val * val;
#pragma unroll
            for (int off = 1; off <= 16; off <<= 1) t2 += __shfl_xor(t2, off, 64);
            if (cl == 0) atomicAdd(&knorm[n * 64 + k], t2);
        }
    }
}

// ---------------- scale: intra-norm (per k) * global norm (per n), in place -
__global__ __launch_bounds__(256) void scale_kernel(float* __restrict__ out,
                                                    const float* __restrict__ knorm) {
    int n = blockIdx.y;
    int sb = blockIdx.x;
    int tid = threadIdx.x;
    __shared__ float sc[64];
    __shared__ float tots;
    if (tid < 64) {
        float kn = knorm[n * 64 + tid];
        float nk = sqrtf(kn);
        float inv = 1.0f / fmaxf(nk, EPSN);
        sc[tid] = inv;
        float t = nk * inv;
        float t2 = t * t;
#pragma unroll
        for (int off = 32; off > 0; off >>= 1) t2 += __shfl_xor(t2, off, 64);
        if (tid == 0) tots = t2;
    }
    __syncthreads();
    float invt = 1.0f / fmaxf(sqrtf(tots), EPSN);
    float* base = out + (size_t)n * 32768 + sb * 4096;
#pragma unroll
    for (int i = 0; i < 16; ++i) {
        int idx = tid + 256 * i;
        int k = (sb * 4096 + idx) >> 9;
        base[idx] *= sc[k] * invt;
    }
}

extern "C" void kernel_launch(void* const* d_in, const int* in_sizes, int n_in,
                              void* d_out, int out_size, void* d_ws, size_t ws_size,
                              hipStream_t stream) {
    const float* x = (const float*)d_in[0];       // [32,512,32,32]
    const float* vocabs = (const float*)d_in[1];  // [64,512]
    float* out = (float*)d_out;                   // [32, 32768]
    char* ws = (char*)d_ws;
    unsigned short* vh = (unsigned short*)(ws);            // 65536 B
    unsigned short* vl = (unsigned short*)(ws + 65536);    // 65536 B
    float* bias  = (float*)(ws + 131072);                  //   256 B
    float* asum  = (float*)(ws + 131328);                  //  8192 B
    float* knorm = (float*)(ws + 139520);                  //  8192 B
    unsigned short* aT = (unsigned short*)(ws + 147712);   // 4 MB : a2 [n][k][p]

    prep_kernel<<<64, 64, 0, stream>>>(vocabs, vh, vl, bias, asum);  // zeroes asum+knorm
    assign_kernel<<<256, 512, 0, stream>>>(x, vh, vl, bias, aT, asum);
    vlad_kernel<<<512, 256, 0, stream>>>(x, aT, asum, vocabs, out, knorm);
    scale_kernel<<<dim3(8, 32), 256, 0, stream>>>(out, knorm);
}